// Round 16
// baseline (719.181 us; speedup 1.0000x reference)
//
#include <hip/hip_runtime.h>
#include <hip/hip_bf16.h>

typedef __attribute__((ext_vector_type(8))) short short8;
typedef float f32x4 __attribute__((ext_vector_type(4)));

#define DIM 512
#define HID 2048
#define ROWSZ (513*512)
#define DT 0.0625f

#define WAITV(n) asm volatile("s_waitcnt vmcnt(" #n ")" ::: "memory")
#define WAITL()  asm volatile("s_waitcnt lgkmcnt(0)" ::: "memory")
#define SBAR()   asm volatile("s_barrier" ::: "memory")
typedef const __attribute__((address_space(1))) void* gas1;
typedef __attribute__((address_space(3))) void* las3;
// aux=1 -> SC0: bypass L1, served by XCD L2 (mutable)
#define GLL16(g,l,aux) __builtin_amdgcn_global_load_lds((gas1)(g),(las3)(l),16,0,aux)
#define GLL4(g,l,aux)  __builtin_amdgcn_global_load_lds((gas1)(g),(las3)(l),4,0,aux)

__device__ __forceinline__ unsigned short f2bfu(float f){ __hip_bfloat16 h=__float2bfloat16(f); return *(unsigned short*)&h; }

// one-time XCD barrier (init only)
__device__ __forceinline__ void xbar(int* arr, int* gen, int target, bool lead){
  asm volatile("s_waitcnt vmcnt(0) lgkmcnt(0)" ::: "memory");
  __syncthreads();
  if (threadIdx.x == 0){
    __hip_atomic_fetch_add(arr, 1, __ATOMIC_RELAXED, __HIP_MEMORY_SCOPE_AGENT);
    if (lead){
      while (__hip_atomic_load(arr, __ATOMIC_RELAXED, __HIP_MEMORY_SCOPE_AGENT) < 32*target)
        __builtin_amdgcn_s_sleep(2);
      __hip_atomic_store(gen, target, __ATOMIC_RELAXED, __HIP_MEMORY_SCOPE_AGENT);
    } else {
      while (__hip_atomic_load(gen, __ATOMIC_RELAXED, __HIP_MEMORY_SCOPE_AGENT) < target)
        __builtin_amdgcn_s_sleep(4);
    }
  }
  __syncthreads();
}

// producer: drain own stores to L2, then post per-wg flag
__device__ __forceinline__ void post_flag(int* f, int seq){
  asm volatile("s_waitcnt vmcnt(0) lgkmcnt(0)" ::: "memory");
  __syncthreads();
  if (threadIdx.x == 0)
    __hip_atomic_store(f, seq, __ATOMIC_RELAXED, __HIP_MEMORY_SCOPE_AGENT);
}
// consumer: one wave polls all 32 per-wg flags (one coalesced L2 line per poll)
__device__ __forceinline__ void wait_flags32(int* base, int seq){
  if (threadIdx.x < 32){
    while (__hip_atomic_load(&base[threadIdx.x], __ATOMIC_RELAXED, __HIP_MEMORY_SCOPE_AGENT) < seq)
      __builtin_amdgcn_s_sleep(2);
  }
  __syncthreads();
}

__global__ __launch_bounds__(512, 1) void k_persist(
    const float* __restrict__ y0, const float* __restrict__ Dy0,
    const float* __restrict__ W1, const float* __restrict__ W2,
    const float* __restrict__ b1, const float* __restrict__ b2,
    unsigned short* __restrict__ Vbuf, unsigned short* __restrict__ tbuf,
    float* __restrict__ yts, unsigned short* __restrict__ a_ss,
    int* __restrict__ ctrl, float* __restrict__ out) {
  __shared__ __align__(16) short W1L[64 * 512];    // 64 KB: wg's 64 W1 cols, K=512, swizzled
  __shared__ __align__(16) short W2L[16 * 2048];   // 64 KB: wg's 16 W2t rows, FULL K, swizzled
  __shared__ __align__(16) short ring[3][4096];    // 24 KB: A-tile ring, 64x64 chunks
  __shared__ float ytL[DIM];                       // 2 KB
  __shared__ __align__(16) unsigned short ytB[DIM]; // 1 KB: bf16 copy of y
  __shared__ __align__(16) unsigned short asL[2048]; // 4 KB (bf16 a, full K)
  __shared__ int bcast[2];
  // total ~159 KB -> 1 wg/CU -> exactly 32 wg/XCD

  const int t = threadIdx.x;
  if (t == 0) {
    int x;
    asm volatile("s_getreg_b32 %0, hwreg(HW_REG_XCC_ID)" : "=s"(x));
    x &= 7;
    bcast[0] = x;
    bcast[1] = atomicAdd(&ctrl[x], 1);
  }
  __syncthreads();
  const int xcd = bcast[0];
  const int sl  = bcast[1] & 31;
  const bool lead = (sl == 0);
  int* arr = ctrl + 64 + xcd * 64;
  int* gen = arr + 32;
  int* flgAb = ctrl + 704 + xcd * 32;   // phase-A done flags, per wg
  int* flgBb = ctrl + 960 + xcd * 32;   // phase-B done flags, per wg

  const int w = t >> 6, lane = t & 63, quad = lane >> 4, l16 = lane & 15;
  const int r8 = lane >> 3;
  const int mX = xcd * 64;
  const int nA = sl * 64;                 // phase A: wg's 64 hidden cols
  const int nB2 = sl * 16;                // phase B: wg's 16 output cols (full K, no wg K-split)
  float* ytx = yts + xcd * DIM;
  unsigned short* asx = a_ss + xcd * HID;

  const int awm = (w & 1) * 32, awn = (w >> 1) * 16;   // phase A: 2m x 4n waves
  const int pj = w >> 1, ph = w & 1;                    // phase B: 4 row-tiles x 2 K-halves

  const short8 z8 = {0,0,0,0,0,0,0,0};

  f32x4 DyR = {0.f,0.f,0.f,0.f}, K1 = DyR, K2 = DyR, K3 = DyR;
  float yR = 0.f, kd1 = 0.f, kd2 = 0.f, kd3 = 0.f;
  const int erow0 = mX + pj * 16 + quad * 4;           // state rows (even waves only)
  const int ecol  = nB2 + l16;
  const float b1v = b1[nA + awn + l16];                // bias for this lane's h column

  auto issueA = [&](int buf, int c) {
    int k0 = c * 64;
    GLL16(Vbuf + (size_t)(mX + w * 8 + r8) * DIM + k0 + (((lane & 7) ^ r8) << 3),
          &ring[buf][(w * 8) * 64], 1);
  };
  auto issueB = [&](int buf, int c) {
    int k0 = c * 64;
    GLL16(tbuf + (size_t)(mX + w * 8 + r8) * HID + k0 + (((lane & 7) ^ r8) << 3),
          &ring[buf][(w * 8) * 64], 1);
  };

  // ---- one-time: fused in-kernel transpose W1,W2 (f32 global) -> bf16 LDS, swizzled ----
  // Physical granule pg holds logical granule lg with pg=(lg&~7)|((lg&7)^(row&7)) (involution,
  // identical to the readers' index math). No W1t/W2t workspace, no transpose kernels.
  {
    // W1 slice: hidden cols nA..nA+63, k 0..511 -> W1L[j][k]
    const int j = t & 63;
    const int kb = (t >> 6) * 64;                       // 8 waves cover 8 k-blocks of 64
    const float* wsrc = W1 + (size_t)kb * HID + (nA + j);
#pragma unroll
    for (int g = 0; g < 8; ++g) {                       // 8 granules of 8 k each
      unsigned short pk[8];
#pragma unroll
      for (int m = 0; m < 8; ++m)
        pk[m] = f2bfu(wsrc[(size_t)(g * 8 + m) * HID]); // wave-coalesced 256B per (g,m)
      int lg = (kb >> 3) + g;
      int pg = (lg & ~7) | ((lg & 7) ^ (j & 7));
      *(short8*)&W1L[j * 512 + pg * 8] = *(short8*)pk;
    }
    // W2 slice: out cols nB2..nB2+15, k 0..2047 -> W2L[j2][k]
    const int j2 = t & 15;
    const int kb2 = (t >> 4) * 64;                      // 32 thread-groups cover 32 k-blocks
    const float* wsrc2 = W2 + (size_t)kb2 * DIM + (nB2 + j2);
#pragma unroll
    for (int g = 0; g < 8; ++g) {
      unsigned short pk[8];
#pragma unroll
      for (int m = 0; m < 8; ++m)
        pk[m] = f2bfu(wsrc2[(size_t)(g * 8 + m) * DIM]);
      int lg = (kb2 >> 3) + g;
      int pg = (lg & ~7) | ((lg & 7) ^ (j2 & 7));
      *(short8*)&W2L[j2 * 2048 + pg * 8] = *(short8*)pk;
    }
  }
  // ---- init state ----
  if (!ph) {
#pragma unroll
    for (int r = 0; r < 4; ++r) {
      float v = Dy0[(size_t)(erow0 + r) * DIM + ecol];
      DyR[r] = v;
      Vbuf[(size_t)(erow0 + r) * DIM + ecol] = f2bfu(v);
      out[DIM + (size_t)(erow0 + r) * DIM + ecol] = v;
    }
  }
  if (t < 16) {
    float v = y0[nB2 + t];
    yR = v;
    ytx[nB2 + t] = v;
    if (xcd == 0) out[nB2 + t] = v;
  }
  WAITV(0);
  __syncthreads();
  xbar(arr, gen, 1, lead);   // one-time init barrier (drains lgkm: W1L/W2L visible)

  for (int ss = 0; ss < 16; ++ss) {
    for (int st = 0; st < 4; ++st) {
      const float cn = (st == 2) ? DT : 0.5f * DT;
      const int seq = ss * 4 + st + 1;
      // ========== PHASE A: g = V @ W1^T (W1 resident); h fused; shfl epilogue ==========
      {
        wait_flags32(flgBb, seq - 1);                     // all wgs done phase B @ seq-1
        GLL4(ytx + w * 64 + lane, &ytL[w * 64], 1);      // oldest load
        issueA(0, 0); issueA(1, 1);
        WAITV(2); SBAR();                                 // ytL landed (all waves)
        ytB[t] = f2bfu(ytL[t]);                           // bf16 copy of y
        f32x4 acc0 = {0.f,0.f,0.f,0.f}, acc1 = acc0, acc2 = acc0;
        short8 ra0[2][2], ra1[2][2], rb[2][2], ya[2][2];
        const int pa0 = awm + l16, pa1 = awm + 16 + l16, pbW = awn + l16;
        WAITV(1); WAITL(); SBAR();                        // slot0 ready + ytB visible
        {
          const short* tA = ring[0];
#pragma unroll
          for (int k2 = 0; k2 < 2; ++k2) {
            int lg = k2 * 4 + quad;
            ra0[0][k2] = *(const short8*)&tA[pa0 * 64 + ((lg ^ (pa0 & 7)) << 3)];
            ra1[0][k2] = *(const short8*)&tA[pa1 * 64 + ((lg ^ (pa1 & 7)) << 3)];
            int gb = lg;
            rb[0][k2] = *(const short8*)&W1L[pbW * 512 + (((gb & ~7) | ((gb & 7) ^ (pbW & 7))) << 3)];
            short8 yv = *(const short8*)&ytB[gb * 8];     // broadcast per quad
            if (l16 != 0) yv = z8;                        // y lives in A-row 0 only
            ya[0][k2] = yv;
          }
        }
        WAITL();                                          // reads done before next SBAR
#pragma unroll
        for (int c = 0; c < 8; ++c) {
          const int pr = c & 1, nx = pr ^ 1;
          if (c < 6)       { issueA((c + 2) % 3, c + 2); WAITV(1); }
          else if (c == 6) { WAITV(0); }
          if (c < 7) {
            SBAR();                                       // slot c+1 globally ready
            const short* tA = ring[(c + 1) % 3];
#pragma unroll
            for (int k2 = 0; k2 < 2; ++k2) {
              int lg = k2 * 4 + quad;
              ra0[nx][k2] = *(const short8*)&tA[pa0 * 64 + ((lg ^ (pa0 & 7)) << 3)];
              ra1[nx][k2] = *(const short8*)&tA[pa1 * 64 + ((lg ^ (pa1 & 7)) << 3)];
              int gb = (c + 1) * 8 + lg;
              rb[nx][k2] = *(const short8*)&W1L[pbW * 512 + (((gb & ~7) | ((gb & 7) ^ (pbW & 7))) << 3)];
              short8 yv = *(const short8*)&ytB[gb * 8];
              if (l16 != 0) yv = z8;
              ya[nx][k2] = yv;
            }
          }
#pragma unroll
          for (int k2 = 0; k2 < 2; ++k2) {
            acc0 = __builtin_amdgcn_mfma_f32_16x16x32_bf16(ra0[pr][k2], rb[pr][k2], acc0, 0, 0, 0);
            acc1 = __builtin_amdgcn_mfma_f32_16x16x32_bf16(ra1[pr][k2], rb[pr][k2], acc1, 0, 0, 0);
            acc2 = __builtin_amdgcn_mfma_f32_16x16x32_bf16(ya[pr][k2],  rb[pr][k2], acc2, 0, 0, 0);
          }
          if (c < 7) WAITL();                             // reads done before wave's next SBAR
        }
        // h[awn+l16] = acc2[0] of quad-0 lane l16 -> wave-local shfl; per-lane tanh
        float hval = __shfl(acc2[0], l16);
        float av = tanhf(hval + b1v);
        float ap = 1.f - av * av;
        const float C1 = ap, C2 = -av * ap;
        if ((w & 1) == 0 && quad == 0) asx[nA + awn + l16] = f2bfu(av);
        int row0 = mX + awm + quad * 4;
        int coln = nA + awn + l16;
#pragma unroll
        for (int r = 0; r < 4; ++r) {
          float g0 = acc0[r], g1 = acc1[r];
          tbuf[(size_t)(row0 + r) * HID + coln]      = f2bfu(g0 * (C1 + C2 * g0));
          tbuf[(size_t)(row0 + 16 + r) * HID + coln] = f2bfu(g1 * (C1 + C2 * g1));
        }
        post_flag(&flgAb[sl], seq);                       // my tbuf/asx cols are in L2
      }
      // ========== PHASE B: dDy = t @ W2 (W2 resident, FULL K; pair K-split in-wg) ==========
      {
        wait_flags32(flgAb, seq);                         // all 32 producers (full K)
        GLL4((const unsigned short*)asx + w * 128 + lane * 2, &asL[w * 128], 1);
        GLL4((const unsigned short*)asx + 1024 + w * 128 + lane * 2, &asL[1024 + w * 128], 1);
        issueB(0, 0); issueB(1, 1);
        WAITV(2); SBAR();                                 // asL landed
        f32x4 acc = {0.f,0.f,0.f,0.f}, acc2 = acc;
        const int paB = pj * 16 + l16;
        const int lgW = ph * 4 + quad;                    // wave-pair K-half within chunk
#pragma unroll
        for (int c = 0; c < 32; ++c) {
          if (c < 31) { WAITV(1); } else { WAITV(0); }
          SBAR();
          if (c < 30) issueB((c + 2) % 3, c + 2);
          const short* tA = ring[c % 3];
          short8 a = *(const short8*)&tA[paB * 64 + ((lgW ^ (paB & 7)) << 3)];
          int gb = c * 8 + lgW;
          short8 b = *(const short8*)&W2L[l16 * 2048 + (((gb & ~7) | ((gb & 7) ^ (l16 & 7))) << 3)];
          short8 av = *(const short8*)&asL[gb * 8];
          if (l16 != 0) av = z8;
          acc  = __builtin_amdgcn_mfma_f32_16x16x32_bf16(a,  b, acc,  0, 0, 0);
          acc2 = __builtin_amdgcn_mfma_f32_16x16x32_bf16(av, b, acc2, 0, 0, 0);
        }
        // pair K-reduce through (drained) ring slot 0
        float* red = (float*)&ring[0][0];
        if (ph) {
#pragma unroll
          for (int r = 0; r < 4; ++r) red[pj * 256 + (quad * 4 + r) * 16 + l16] = acc[r];
          if (w == 1 && quad == 0) red[1024 + l16] = acc2[0];
        }
        WAITL(); SBAR();
        if (!ph) {
          f32x4 o;
#pragma unroll
          for (int r = 0; r < 4; ++r) o[r] = acc[r] + red[pj * 256 + (quad * 4 + r) * 16 + l16];
          if (st == 0) K1 = o; else if (st == 1) K2 = o; else if (st == 2) K3 = o;
          if (st < 3) {
#pragma unroll
            for (int r = 0; r < 4; ++r) {
              float v = DyR[r] + cn * o[r];
              Vbuf[(size_t)(erow0 + r) * DIM + ecol] = f2bfu(v);
            }
          } else {
            const float dt6 = DT / 6.f;
#pragma unroll
            for (int r = 0; r < 4; ++r) {
              float v = DyR[r] + dt6 * (K1[r] + 2.f * K2[r] + 2.f * K3[r] + o[r]);
              DyR[r] = v;
              Vbuf[(size_t)(erow0 + r) * DIM + ecol] = f2bfu(v);
              if (ss & 1) out[(size_t)(ss / 2 + 1) * ROWSZ + DIM + (size_t)(erow0 + r) * DIM + ecol] = v;
            }
          }
        }
        if (t < 16) {                                     // w==0, quad==0 lanes: full dy = own half + partner half
          float k4 = acc2[0] + red[1024 + t] + b2[nB2 + t];
          if (st == 0) kd1 = k4; else if (st == 1) kd2 = k4; else if (st == 2) kd3 = k4;
          if (st < 3) {
            ytx[nB2 + t] = yR + cn * k4;
          } else {
            yR += (DT / 6.f) * (kd1 + 2.f * kd2 + 2.f * kd3 + k4);
            ytx[nB2 + t] = yR;
            if ((ss & 1) && xcd == 0) out[(size_t)(ss / 2 + 1) * ROWSZ + nB2 + t] = yR;
          }
        }
        post_flag(&flgBb[sl], seq);                       // Vbuf/ytx @ seq in L2
      }
    }
  }
}

extern "C" void kernel_launch(void* const* d_in, const int* in_sizes, int n_in,
                              void* d_out, int out_size, void* d_ws, size_t ws_size,
                              hipStream_t stream) {
  const float* y0  = (const float*)d_in[1];
  const float* Dy0 = (const float*)d_in[2];
  const float* W1  = (const float*)d_in[3];
  const float* b1  = (const float*)d_in[4];
  const float* W2  = (const float*)d_in[5];
  const float* b2  = (const float*)d_in[6];
  float* out = (float*)d_out;

  char* p = (char*)d_ws;
  auto alloc = [&](size_t bytes) {
    char* r = p;
    p += (bytes + 255) & ~(size_t)255;
    return r;
  };
  unsigned short* Vbuf = (unsigned short*)alloc((size_t)DIM * DIM * 2);
  unsigned short* tbuf = (unsigned short*)alloc((size_t)DIM * HID * 2);
  float* yts  = (float*)alloc(8 * DIM * 4);
  unsigned short* a_ss = (unsigned short*)alloc(8 * HID * 2);
  int* ctrl   = (int*)alloc(8192);

  hipMemsetAsync(ctrl, 0, 8192, stream);
  k_persist<<<256, 512, 0, stream>>>(y0, Dy0, W1, W2, b1, b2,
                                     Vbuf, tbuf, yts, a_ss, ctrl, out);
}

// Round 17
// 698.260 us; speedup vs baseline: 1.0300x; 1.0300x over previous
//
#include <hip/hip_runtime.h>
#include <hip/hip_bf16.h>

typedef __attribute__((ext_vector_type(8))) short short8;
typedef float f32x4 __attribute__((ext_vector_type(4)));

#define DIM 512
#define HID 2048
#define ROWSZ (513*512)
#define DT 0.0625f

#define WAITV(n) asm volatile("s_waitcnt vmcnt(" #n ")" ::: "memory")
#define WAITL()  asm volatile("s_waitcnt lgkmcnt(0)" ::: "memory")
#define SBAR()   asm volatile("s_barrier" ::: "memory")
typedef const __attribute__((address_space(1))) void* gas1;
typedef __attribute__((address_space(3))) void* las3;
// aux=1 -> SC0: bypass L1, served by XCD L2 (mutable); aux=0 -> one-time weight loads
#define GLL16(g,l,aux) __builtin_amdgcn_global_load_lds((gas1)(g),(las3)(l),16,0,aux)
#define GLL4(g,l,aux)  __builtin_amdgcn_global_load_lds((gas1)(g),(las3)(l),4,0,aux)

__device__ __forceinline__ unsigned short f2bfu(float f){ __hip_bfloat16 h=__float2bfloat16(f); return *(unsigned short*)&h; }

// one-time XCD barrier (init only)
__device__ __forceinline__ void xbar(int* arr, int* gen, int target, bool lead){
  asm volatile("s_waitcnt vmcnt(0) lgkmcnt(0)" ::: "memory");
  __syncthreads();
  if (threadIdx.x == 0){
    __hip_atomic_fetch_add(arr, 1, __ATOMIC_RELAXED, __HIP_MEMORY_SCOPE_AGENT);
    if (lead){
      while (__hip_atomic_load(arr, __ATOMIC_RELAXED, __HIP_MEMORY_SCOPE_AGENT) < 32*target)
        __builtin_amdgcn_s_sleep(2);
      __hip_atomic_store(gen, target, __ATOMIC_RELAXED, __HIP_MEMORY_SCOPE_AGENT);
    } else {
      while (__hip_atomic_load(gen, __ATOMIC_RELAXED, __HIP_MEMORY_SCOPE_AGENT) < target)
        __builtin_amdgcn_s_sleep(4);
    }
  }
  __syncthreads();
}

// producer: drain own stores to L2, then post per-wg flag
__device__ __forceinline__ void post_flag(int* f, int seq){
  asm volatile("s_waitcnt vmcnt(0) lgkmcnt(0)" ::: "memory");
  __syncthreads();
  if (threadIdx.x == 0)
    __hip_atomic_store(f, seq, __ATOMIC_RELAXED, __HIP_MEMORY_SCOPE_AGENT);
}
// consumer: one wave polls all 32 per-wg flags (one coalesced L2 line per poll)
__device__ __forceinline__ void wait_flags32(int* base, int seq){
  if (threadIdx.x < 32){
    while (__hip_atomic_load(&base[threadIdx.x], __ATOMIC_RELAXED, __HIP_MEMORY_SCOPE_AGENT) < seq)
      __builtin_amdgcn_s_sleep(2);
  }
  __syncthreads();
}

// Fused prep: both weight transposes in one launch + ctrl memset in block 0.
// W1 tiles: blocks [0,1024): c-block = b&63 (HID/32), r-block = b>>6 (DIM/32).
// W2 tiles: blocks [1024,2048): c-block = b&15 (DIM/32), r-block = b>>4 (HID/32).
__global__ void k_prep(const float* __restrict__ W1, const float* __restrict__ W2,
                       __hip_bfloat16* __restrict__ W1t, __hip_bfloat16* __restrict__ W2t,
                       int* __restrict__ ctrl) {
  __shared__ float tile[32][33];
  int b = blockIdx.x;
  if (b == 0) {
#pragma unroll
    for (int i = 0; i < 8; ++i) ctrl[threadIdx.x * 8 + i] = 0;   // 256 thr x 8 = 2048 ints = 8 KB
  }
  const float* src; __hip_bfloat16* dst; int R, C, c0, r0;
  if (b < 1024) { src = W1; dst = W1t; R = DIM; C = HID; c0 = (b & 63) * 32; r0 = (b >> 6) * 32; }
  else { b -= 1024; src = W2; dst = W2t; R = HID; C = DIM; c0 = (b & 15) * 32; r0 = (b >> 4) * 32; }
  int tx = threadIdx.x & 31, ty = threadIdx.x >> 5;
  for (int i = 0; i < 32; i += 8)
    tile[ty + i][tx] = src[(size_t)(r0 + ty + i) * C + c0 + tx];
  __syncthreads();
  for (int i = 0; i < 32; i += 8)
    dst[(size_t)(c0 + ty + i) * R + r0 + tx] = __float2bfloat16(tile[tx][ty + i]);
}

__global__ __launch_bounds__(512, 1) void k_persist(
    const float* __restrict__ y0, const float* __restrict__ Dy0,
    const unsigned short* __restrict__ W1t, const unsigned short* __restrict__ W2t,
    const float* __restrict__ b1, const float* __restrict__ b2,
    unsigned short* __restrict__ Vbuf, unsigned short* __restrict__ tbuf,
    float* __restrict__ yts, unsigned short* __restrict__ a_ss, float* __restrict__ pbuf,
    int* __restrict__ ctrl, float* __restrict__ out) {
  __shared__ __align__(16) short W1L[64 * 512];    // 64 KB: wg's 64 W1 cols, K=512, swizzled
  __shared__ __align__(16) short W2L[16 * 2048];   // 64 KB: wg's 16 W2t rows, FULL K, swizzled
  __shared__ __align__(16) short ring[3][4096];    // 24 KB: A-tile ring, 64x64 chunks
  __shared__ float ytL[DIM];                       // 2 KB
  __shared__ __align__(16) unsigned short ytB[DIM]; // 1 KB: bf16 copy of y
  __shared__ __align__(16) unsigned short asL[2048]; // 4 KB (bf16 a, full K)
  __shared__ int bcast[2];
  // total ~159 KB -> 1 wg/CU -> exactly 32 wg/XCD

  const int t = threadIdx.x;
  if (t == 0) {
    int x;
    asm volatile("s_getreg_b32 %0, hwreg(HW_REG_XCC_ID)" : "=s"(x));
    x &= 7;
    bcast[0] = x;
    bcast[1] = atomicAdd(&ctrl[x], 1);
  }
  __syncthreads();
  const int xcd = bcast[0];
  const int sl  = bcast[1] & 31;
  const bool lead = (sl == 0);
  int* arr = ctrl + 64 + xcd * 64;
  int* gen = arr + 32;
  int* flgAb = ctrl + 704 + xcd * 32;   // phase-A done flags, per wg
  int* flgBb = ctrl + 960 + xcd * 32;   // phase-B done flags, per wg

  const int w = t >> 6, lane = t & 63, quad = lane >> 4, l16 = lane & 15;
  const int r8 = lane >> 3;
  const int mX = xcd * 64;
  const int nA = sl * 64;                 // phase A: wg's 64 hidden cols
  const int nB2 = sl * 16;                // phase B: wg's 16 output cols (full K, no wg K-split)
  float* ytx = yts + xcd * DIM;
  unsigned short* asx = a_ss + xcd * HID;

  const int awm = (w & 1) * 32, awn = (w >> 1) * 16;   // phase A: 2m x 4n waves
  const int pj = w >> 1, ph = w & 1;                    // phase B: 4 row-tiles x 2 K-halves

  const short8 z8 = {0,0,0,0,0,0,0,0};

  f32x4 DyR = {0.f,0.f,0.f,0.f}, K1 = DyR, K2 = DyR, K3 = DyR;
  float yR = 0.f, kd1 = 0.f, kd2 = 0.f, kd3 = 0.f;
  const int erow0 = mX + pj * 16 + quad * 4;           // state rows (even waves only)
  const int ecol  = nB2 + l16;
  const float b1v = b1[nA + awn + l16];                // bias for this lane's h column

  auto issueA = [&](int buf, int c) {
    int k0 = c * 64;
    GLL16(Vbuf + (size_t)(mX + w * 8 + r8) * DIM + k0 + (((lane & 7) ^ r8) << 3),
          &ring[buf][(w * 8) * 64], 1);
  };
  auto issueB = [&](int buf, int c) {
    int k0 = c * 64;
    GLL16(tbuf + (size_t)(mX + w * 8 + r8) * HID + k0 + (((lane & 7) ^ r8) << 3),
          &ring[buf][(w * 8) * 64], 1);
  };

  // ---- one-time: weights -> LDS (swizzled: phys granule p holds logical (p&~7)|((p&7)^(r&7))) ----
#pragma unroll
  for (int i = 0; i < 8; ++i) {
    int r = w * 8 + i;
    int src = ((lane & ~7) | ((lane & 7) ^ (r & 7))) << 3;
    GLL16(W1t + (size_t)(nA + r) * DIM + src, &W1L[r * 512], 0);
  }
#pragma unroll
  for (int i = 0; i < 2; ++i) {
    int r = w * 2 + i;
#pragma unroll
    for (int j = 0; j < 4; ++j) {
      int g0 = j * 64 + lane;
      int src = ((g0 & ~7) | ((g0 & 7) ^ (r & 7))) << 3;
      GLL16(W2t + (size_t)(nB2 + r) * HID + src, &W2L[r * 2048 + j * 512], 0);
    }
  }
  // ---- init state ----
  if (!ph) {
#pragma unroll
    for (int r = 0; r < 4; ++r) {
      float v = Dy0[(size_t)(erow0 + r) * DIM + ecol];
      DyR[r] = v;
      Vbuf[(size_t)(erow0 + r) * DIM + ecol] = f2bfu(v);
      out[DIM + (size_t)(erow0 + r) * DIM + ecol] = v;
    }
  }
  if (t < 16) {
    float v = y0[nB2 + t];
    yR = v;
    ytx[nB2 + t] = v;
    if (xcd == 0) out[nB2 + t] = v;
  }
  WAITV(0);
  __syncthreads();
  xbar(arr, gen, 1, lead);   // one-time init barrier

  for (int ss = 0; ss < 16; ++ss) {
    for (int st = 0; st < 4; ++st) {
      const float cn = (st == 2) ? DT : 0.5f * DT;
      const int seq = ss * 4 + st + 1;
      // ========== PHASE A: g = V @ W1^T (W1 resident); h fused; shfl epilogue (no LDS/barriers) ==========
      {
        wait_flags32(flgBb, seq - 1);                     // all wgs done phase B @ seq-1
        GLL4(ytx + w * 64 + lane, &ytL[w * 64], 1);      // oldest load
        issueA(0, 0); issueA(1, 1);
        WAITV(2); SBAR();                                 // ytL landed (all waves)
        ytB[t] = f2bfu(ytL[t]);                           // bf16 copy of y
        f32x4 acc0 = {0.f,0.f,0.f,0.f}, acc1 = acc0, acc2 = acc0;
        short8 ra0[2][2], ra1[2][2], rb[2][2], ya[2][2];
        const int pa0 = awm + l16, pa1 = awm + 16 + l16, pbW = awn + l16;
        WAITV(1); WAITL(); SBAR();                        // slot0 ready + ytB visible
        {
          const short* tA = ring[0];
#pragma unroll
          for (int k2 = 0; k2 < 2; ++k2) {
            int lg = k2 * 4 + quad;
            ra0[0][k2] = *(const short8*)&tA[pa0 * 64 + ((lg ^ (pa0 & 7)) << 3)];
            ra1[0][k2] = *(const short8*)&tA[pa1 * 64 + ((lg ^ (pa1 & 7)) << 3)];
            int gb = lg;
            rb[0][k2] = *(const short8*)&W1L[pbW * 512 + (((gb & ~7) | ((gb & 7) ^ (pbW & 7))) << 3)];
            short8 yv = *(const short8*)&ytB[gb * 8];     // broadcast per quad
            if (l16 != 0) yv = z8;                        // y lives in A-row 0 only
            ya[0][k2] = yv;
          }
        }
        WAITL();                                          // reads done before next SBAR
#pragma unroll
        for (int c = 0; c < 8; ++c) {
          const int pr = c & 1, nx = pr ^ 1;
          if (c < 6)       { issueA((c + 2) % 3, c + 2); WAITV(1); }
          else if (c == 6) { WAITV(0); }
          if (c < 7) {
            SBAR();                                       // slot c+1 globally ready
            const short* tA = ring[(c + 1) % 3];
#pragma unroll
            for (int k2 = 0; k2 < 2; ++k2) {
              int lg = k2 * 4 + quad;
              ra0[nx][k2] = *(const short8*)&tA[pa0 * 64 + ((lg ^ (pa0 & 7)) << 3)];
              ra1[nx][k2] = *(const short8*)&tA[pa1 * 64 + ((lg ^ (pa1 & 7)) << 3)];
              int gb = (c + 1) * 8 + lg;
              rb[nx][k2] = *(const short8*)&W1L[pbW * 512 + (((gb & ~7) | ((gb & 7) ^ (pbW & 7))) << 3)];
              short8 yv = *(const short8*)&ytB[gb * 8];
              if (l16 != 0) yv = z8;
              ya[nx][k2] = yv;
            }
          }
#pragma unroll
          for (int k2 = 0; k2 < 2; ++k2) {
            acc0 = __builtin_amdgcn_mfma_f32_16x16x32_bf16(ra0[pr][k2], rb[pr][k2], acc0, 0, 0, 0);
            acc1 = __builtin_amdgcn_mfma_f32_16x16x32_bf16(ra1[pr][k2], rb[pr][k2], acc1, 0, 0, 0);
            acc2 = __builtin_amdgcn_mfma_f32_16x16x32_bf16(ya[pr][k2],  rb[pr][k2], acc2, 0, 0, 0);
          }
          if (c < 7) WAITL();                             // reads done before wave's next SBAR
        }
        // h[awn+l16] = acc2[0] of quad-0 lane l16 (identical on every wave) -> wave-local shfl,
        // tanh/C1/C2 computed per-lane redundantly; no pacc/c1L/c2L, no epilogue barriers.
        float hval = __shfl(acc2[0], l16);
        float av = tanhf(hval + b1v);
        float ap = 1.f - av * av;
        const float C1 = ap, C2 = -av * ap;
        if ((w & 1) == 0 && quad == 0) asx[nA + awn + l16] = f2bfu(av);
        int row0 = mX + awm + quad * 4;
        int coln = nA + awn + l16;
#pragma unroll
        for (int r = 0; r < 4; ++r) {
          float g0 = acc0[r], g1 = acc1[r];
          tbuf[(size_t)(row0 + r) * HID + coln]      = f2bfu(g0 * (C1 + C2 * g0));
          tbuf[(size_t)(row0 + 16 + r) * HID + coln] = f2bfu(g1 * (C1 + C2 * g1));
        }
        post_flag(&flgAb[sl], seq);                       // my tbuf/asx cols are in L2
      }
      // ========== PHASE B: dDy = t @ W2 (W2 resident, FULL K; pair K-split in-wg) ==========
      {
        wait_flags32(flgAb, seq);                         // all 32 producers (full K)
        GLL4((const unsigned short*)asx + w * 128 + lane * 2, &asL[w * 128], 1);
        GLL4((const unsigned short*)asx + 1024 + w * 128 + lane * 2, &asL[1024 + w * 128], 1);
        issueB(0, 0); issueB(1, 1);
        WAITV(2); SBAR();                                 // asL landed
        f32x4 acc = {0.f,0.f,0.f,0.f}, acc2 = acc;
        const int paB = pj * 16 + l16;
        const int lgW = ph * 4 + quad;                    // wave-pair K-half within chunk
#pragma unroll
        for (int c = 0; c < 32; ++c) {
          if (c < 31) { WAITV(1); } else { WAITV(0); }
          SBAR();
          if (c < 30) issueB((c + 2) % 3, c + 2);
          const short* tA = ring[c % 3];
          short8 a = *(const short8*)&tA[paB * 64 + ((lgW ^ (paB & 7)) << 3)];
          int gb = c * 8 + lgW;
          short8 b = *(const short8*)&W2L[l16 * 2048 + (((gb & ~7) | ((gb & 7) ^ (l16 & 7))) << 3)];
          short8 av = *(const short8*)&asL[gb * 8];
          if (l16 != 0) av = z8;
          acc  = __builtin_amdgcn_mfma_f32_16x16x32_bf16(a,  b, acc,  0, 0, 0);
          acc2 = __builtin_amdgcn_mfma_f32_16x16x32_bf16(av, b, acc2, 0, 0, 0);
        }
        // pair K-reduce through (drained) ring slot 0
        float* red = (float*)&ring[0][0];
        if (ph) {
#pragma unroll
          for (int r = 0; r < 4; ++r) red[pj * 256 + (quad * 4 + r) * 16 + l16] = acc[r];
          if (w == 1 && quad == 0) red[1024 + l16] = acc2[0];
        }
        WAITL(); SBAR();
        if (!ph) {
          f32x4 o;
#pragma unroll
          for (int r = 0; r < 4; ++r) o[r] = acc[r] + red[pj * 256 + (quad * 4 + r) * 16 + l16];
          if (st == 0) K1 = o; else if (st == 1) K2 = o; else if (st == 2) K3 = o;
          if (st < 3) {
#pragma unroll
            for (int r = 0; r < 4; ++r) {
              float v = DyR[r] + cn * o[r];
              Vbuf[(size_t)(erow0 + r) * DIM + ecol] = f2bfu(v);
            }
          } else {
            const float dt6 = DT / 6.f;
#pragma unroll
            for (int r = 0; r < 4; ++r) {
              float v = DyR[r] + dt6 * (K1[r] + 2.f * K2[r] + 2.f * K3[r] + o[r]);
              DyR[r] = v;
              Vbuf[(size_t)(erow0 + r) * DIM + ecol] = f2bfu(v);
              if (ss & 1) out[(size_t)(ss / 2 + 1) * ROWSZ + DIM + (size_t)(erow0 + r) * DIM + ecol] = v;
            }
          }
        }
        if (t < 16) {                                     // w==0, quad==0 lanes: full dy = own half + partner half
          float k4 = acc2[0] + red[1024 + t] + b2[nB2 + t];
          if (st == 0) kd1 = k4; else if (st == 1) kd2 = k4; else if (st == 2) kd3 = k4;
          if (st < 3) {
            ytx[nB2 + t] = yR + cn * k4;
          } else {
            yR += (DT / 6.f) * (kd1 + 2.f * kd2 + 2.f * kd3 + k4);
            ytx[nB2 + t] = yR;
            if ((ss & 1) && xcd == 0) out[(size_t)(ss / 2 + 1) * ROWSZ + nB2 + t] = yR;
          }
        }
        post_flag(&flgBb[sl], seq);                       // Vbuf/ytx @ seq in L2
      }
    }
  }
}

extern "C" void kernel_launch(void* const* d_in, const int* in_sizes, int n_in,
                              void* d_out, int out_size, void* d_ws, size_t ws_size,
                              hipStream_t stream) {
  const float* y0  = (const float*)d_in[1];
  const float* Dy0 = (const float*)d_in[2];
  const float* W1  = (const float*)d_in[3];
  const float* b1  = (const float*)d_in[4];
  const float* W2  = (const float*)d_in[5];
  const float* b2  = (const float*)d_in[6];
  float* out = (float*)d_out;

  char* p = (char*)d_ws;
  auto alloc = [&](size_t bytes) {
    char* r = p;
    p += (bytes + 255) & ~(size_t)255;
    return r;
  };
  unsigned short* W1t  = (unsigned short*)alloc((size_t)HID * DIM * 2);
  unsigned short* W2t  = (unsigned short*)alloc((size_t)DIM * HID * 2);
  unsigned short* Vbuf = (unsigned short*)alloc((size_t)DIM * DIM * 2);
  unsigned short* tbuf = (unsigned short*)alloc((size_t)DIM * HID * 2);
  float* yts  = (float*)alloc(8 * DIM * 4);
  unsigned short* a_ss = (unsigned short*)alloc(8 * HID * 2);
  float* pbuf = (float*)alloc((size_t)8 * 16 * 2112 * 4);
  int* ctrl   = (int*)alloc(8192);

  // single prep launch: both transposes + ctrl zeroing (block 0)
  k_prep<<<2048, 256, 0, stream>>>(W1, W2, (__hip_bfloat16*)W1t, (__hip_bfloat16*)W2t, ctrl);
  k_persist<<<256, 512, 0, stream>>>(y0, Dy0, W1t, W2t, b1, b2,
                                     Vbuf, tbuf, yts, a_ss, pbuf, ctrl, out);
}